// Round 2
// baseline (337.992 us; speedup 1.0000x reference)
//
#include <hip/hip_runtime.h>
#include <stdint.h>

#define NPOS  33600
#define KTOP  1000
#define NBIN  2048
#define CAP   4096

// sizes per level
#define HW0 25600  // 160x160, stride 8
#define HW1 6400   // 80x80,  stride 16
#define HW2 1600   // 40x40,  stride 32

#define NF4   (NPOS / 4)   // 8400 float4 per batch
#define CHUNKS 16          // blocks per batch for sweep kernels
#define SWTH  256          // threads for sweep kernels

__device__ __forceinline__ uint32_t mono_key(float x) {
    uint32_t u = __float_as_uint(x);
    return (u & 0x80000000u) ? ~u : (u | 0x80000000u);
}

__device__ __forceinline__ float load_cls(const float* cb0, const float* cb1,
                                          const float* cb2, int i) {
    if (i < HW0)            return cb0[i];
    if (i < HW0 + HW1)      return cb1[i - HW0];
    return cb2[i - HW0 - HW1];
}

// float4 load of elements [4*i4 .. 4*i4+3] (level boundaries are /4)
__device__ __forceinline__ float4 load_cls4(const float* cb0, const float* cb1,
                                            const float* cb2, int i4) {
    int i = i4 * 4;
    if (i < HW0)            return ((const float4*)cb0)[i4];
    if (i < HW0 + HW1)      return ((const float4*)(cb1))[i4 - HW0 / 4];
    return ((const float4*)(cb2))[i4 - (HW0 + HW1) / 4];
}

// ---------------- K1: per-batch histogram, full-GPU parallel ----------------
__global__ __launch_bounds__(SWTH) void k1_hist(
    const float* __restrict__ cls0, const float* __restrict__ cls1,
    const float* __restrict__ cls2, uint32_t* __restrict__ g_hist)
{
    const int b = blockIdx.x / CHUNKS;
    const int c = blockIdx.x % CHUNKS;
    const int tid = threadIdx.x;

    __shared__ uint32_t hist[NBIN];
    for (int i = tid; i < NBIN; i += SWTH) hist[i] = 0u;
    __syncthreads();

    const float* cb0 = cls0 + (size_t)b * HW0;
    const float* cb1 = cls1 + (size_t)b * HW1;
    const float* cb2 = cls2 + (size_t)b * HW2;

    const int per = (NF4 + CHUNKS - 1) / CHUNKS;      // 525
    const int lo = c * per;
    const int hi = min(lo + per, NF4);
    for (int i4 = lo + tid; i4 < hi; i4 += SWTH) {
        float4 v = load_cls4(cb0, cb1, cb2, i4);
        atomicAdd(&hist[mono_key(v.x) >> 21], 1u);
        atomicAdd(&hist[mono_key(v.y) >> 21], 1u);
        atomicAdd(&hist[mono_key(v.z) >> 21], 1u);
        atomicAdd(&hist[mono_key(v.w) >> 21], 1u);
    }
    __syncthreads();

    uint32_t* gh = g_hist + (size_t)b * NBIN;
    for (int i = tid; i < NBIN; i += SWTH) {
        uint32_t h = hist[i];
        if (h) atomicAdd(&gh[i], h);
    }
}

// ---------------- K2: suffix scan -> boundary per batch ----------------
__global__ __launch_bounds__(SWTH) void k2_boundary(
    const uint32_t* __restrict__ g_hist, uint32_t* __restrict__ g_boundary,
    uint32_t* __restrict__ g_cnt)
{
    const int b = blockIdx.x;
    const int tid = threadIdx.x;
    __shared__ uint32_t hA[NBIN];
    __shared__ uint32_t hB[NBIN];

    const uint32_t* gh = g_hist + (size_t)b * NBIN;
    for (int i = tid; i < NBIN; i += SWTH) hA[i] = gh[i];
    __syncthreads();

    uint32_t* A = hA; uint32_t* Bp = hB;
    for (int off = 1; off < NBIN; off <<= 1) {
        for (int i = tid; i < NBIN; i += SWTH)
            Bp[i] = A[i] + ((i + off < NBIN) ? A[i + off] : 0u);
        __syncthreads();
        uint32_t* t = A; A = Bp; Bp = t;
    }
    for (int bin = tid; bin < NBIN; bin += SWTH) {
        uint32_t c     = A[bin];
        uint32_t cnext = (bin + 1 < NBIN) ? A[bin + 1] : 0u;
        if (c >= (uint32_t)KTOP && cnext < (uint32_t)KTOP) g_boundary[b] = (uint32_t)bin;
    }
    if (tid == 0) g_cnt[b] = 0u;
}

// ---------------- K3: compact candidates, full-GPU parallel ----------------
__global__ __launch_bounds__(SWTH) void k3_compact(
    const float* __restrict__ cls0, const float* __restrict__ cls1,
    const float* __restrict__ cls2, const uint32_t* __restrict__ g_boundary,
    uint32_t* __restrict__ g_cnt, unsigned long long* __restrict__ g_cand)
{
    const int b = blockIdx.x / CHUNKS;
    const int c = blockIdx.x % CHUNKS;
    const int tid = threadIdx.x;

    const uint32_t boundary = g_boundary[b];
    const float* cb0 = cls0 + (size_t)b * HW0;
    const float* cb1 = cls1 + (size_t)b * HW1;
    const float* cb2 = cls2 + (size_t)b * HW2;
    unsigned long long* cand = g_cand + (size_t)b * CAP;
    uint32_t* cnt = g_cnt + b;

    const int per = (NF4 + CHUNKS - 1) / CHUNKS;
    const int lo = c * per;
    const int hi = min(lo + per, NF4);
    for (int i4 = lo + tid; i4 < hi; i4 += SWTH) {
        float4 v = load_cls4(cb0, cb1, cb2, i4);
        float vv[4] = {v.x, v.y, v.z, v.w};
        #pragma unroll
        for (int e = 0; e < 4; e++) {
            uint32_t k = mono_key(vv[e]);
            if ((k >> 21) >= boundary) {
                uint32_t pos = atomicAdd(cnt, 1u);
                if (pos < CAP) {
                    int idx = i4 * 4 + e;
                    cand[pos] = ((unsigned long long)k << 16)
                              | (unsigned long long)(65535 - idx);
                }
            }
        }
    }
}

// ---------------- K4: sort + decode + write ----------------
__global__ __launch_bounds__(1024) void k4_sort_out(
    const float* __restrict__ bb0, const float* __restrict__ bb1,
    const float* __restrict__ bb2, const uint32_t* __restrict__ g_cnt,
    const unsigned long long* __restrict__ g_cand,
    float* __restrict__ out, int B)
{
    const int b = blockIdx.x;
    const int tid = threadIdx.x;
    __shared__ unsigned long long buf[CAP];

    int cnt = (int)g_cnt[b]; if (cnt > CAP) cnt = CAP;
    const unsigned long long* cand = g_cand + (size_t)b * CAP;
    for (int i = tid; i < cnt; i += 1024) buf[i] = cand[i];

    int M = 1024; while (M < cnt) M <<= 1;
    for (int i = cnt + tid; i < M; i += 1024) buf[i] = 0ull;
    __syncthreads();

    for (int k = 2; k <= M; k <<= 1) {
        for (int j = k >> 1; j > 0; j >>= 1) {
            for (int i = tid; i < M; i += 1024) {
                int l = i ^ j;
                if (l > i) {
                    unsigned long long a = buf[i], c2 = buf[l];
                    bool sw = ((i & k) == 0) ? (a < c2) : (a > c2);
                    if (sw) { buf[i] = c2; buf[l] = a; }
                }
            }
            __syncthreads();
        }
    }

    const size_t score_base = (size_t)B * KTOP * 4;
    for (int r = tid; r < KTOP; r += 1024) {
        unsigned long long ck = buf[r];
        uint32_t k = (uint32_t)(ck >> 16);
        int idx    = 65535 - (int)(ck & 0xFFFFull);

        uint32_t u = (k & 0x80000000u) ? (k ^ 0x80000000u) : ~k;
        float logit = __uint_as_float(u);
        float score = 1.0f / (1.0f + expf(-logit));

        int j, w, stride, hw;
        const float* bb;
        if (idx < HW0)            { j = idx;             w = 160; stride = 8;  hw = HW0; bb = bb0 + (size_t)b * 4 * HW0; }
        else if (idx < HW0 + HW1) { j = idx - HW0;       w = 80;  stride = 16; hw = HW1; bb = bb1 + (size_t)b * 4 * HW1; }
        else                      { j = idx - HW0 - HW1; w = 40;  stride = 32; hw = HW2; bb = bb2 + (size_t)b * 4 * HW2; }

        float px = (float)((j % w) * stride);
        float py = (float)((j / w) * stride);
        float l0 = bb[j];
        float t0 = bb[hw + j];
        float r0 = bb[2 * hw + j];
        float d0 = bb[3 * hw + j];

        float* ob = out + ((size_t)b * KTOP + r) * 4;
        ob[0] = px - l0;
        ob[1] = py - t0;
        ob[2] = px + r0;
        ob[3] = py + d0;
        out[score_base + (size_t)b * KTOP + r] = score;
    }
}

// ---------------- fallback: round-1 monolithic kernel ----------------
__global__ __launch_bounds__(1024) void topk_decode_kernel(
    const float* __restrict__ cls0, const float* __restrict__ bb0,
    const float* __restrict__ cls1, const float* __restrict__ bb1,
    const float* __restrict__ cls2, const float* __restrict__ bb2,
    float* __restrict__ out, int B)
{
    const int b   = blockIdx.x;
    const int tid = threadIdx.x;

    __shared__ uint32_t histA[NBIN];
    __shared__ uint32_t histB[NBIN];
    __shared__ unsigned long long buf[CAP];
    __shared__ int s_boundary;
    __shared__ int s_cnt;

    for (int i = tid; i < NBIN; i += 1024) histA[i] = 0u;
    if (tid == 0) s_cnt = 0;
    __syncthreads();

    const float* cb0 = cls0 + (size_t)b * HW0;
    const float* cb1 = cls1 + (size_t)b * HW1;
    const float* cb2 = cls2 + (size_t)b * HW2;

    for (int i = tid; i < NPOS; i += 1024) {
        float v = load_cls(cb0, cb1, cb2, i);
        atomicAdd(&histA[mono_key(v) >> 21], 1u);
    }
    __syncthreads();

    uint32_t* A = histA; uint32_t* Bp = histB;
    for (int off = 1; off < NBIN; off <<= 1) {
        for (int i = tid; i < NBIN; i += 1024)
            Bp[i] = A[i] + ((i + off < NBIN) ? A[i + off] : 0u);
        __syncthreads();
        uint32_t* t = A; A = Bp; Bp = t;
    }
    for (int bin = tid; bin < NBIN; bin += 1024) {
        uint32_t c     = A[bin];
        uint32_t cnext = (bin + 1 < NBIN) ? A[bin + 1] : 0u;
        if (c >= (uint32_t)KTOP && cnext < (uint32_t)KTOP) s_boundary = bin;
    }
    __syncthreads();
    const uint32_t boundary = (uint32_t)s_boundary;

    for (int i = tid; i < NPOS; i += 1024) {
        float v = load_cls(cb0, cb1, cb2, i);
        uint32_t k = mono_key(v);
        if ((k >> 21) >= boundary) {
            int pos = atomicAdd(&s_cnt, 1);
            if (pos < CAP)
                buf[pos] = ((unsigned long long)k << 16)
                         | (unsigned long long)(65535 - i);
        }
    }
    __syncthreads();
    int cnt = s_cnt; if (cnt > CAP) cnt = CAP;
    int M = 1024; while (M < cnt) M <<= 1;
    for (int i = cnt + tid; i < M; i += 1024) buf[i] = 0ull;
    __syncthreads();

    for (int k = 2; k <= M; k <<= 1) {
        for (int j = k >> 1; j > 0; j >>= 1) {
            for (int i = tid; i < M; i += 1024) {
                int l = i ^ j;
                if (l > i) {
                    unsigned long long a = buf[i], c = buf[l];
                    bool sw = ((i & k) == 0) ? (a < c) : (a > c);
                    if (sw) { buf[i] = c; buf[l] = a; }
                }
            }
            __syncthreads();
        }
    }

    const size_t score_base = (size_t)B * KTOP * 4;
    for (int r = tid; r < KTOP; r += 1024) {
        unsigned long long ck = buf[r];
        uint32_t k = (uint32_t)(ck >> 16);
        int idx    = 65535 - (int)(ck & 0xFFFFull);

        uint32_t u = (k & 0x80000000u) ? (k ^ 0x80000000u) : ~k;
        float logit = __uint_as_float(u);
        float score = 1.0f / (1.0f + expf(-logit));

        int j, w, stride, hw;
        const float* bb;
        if (idx < HW0)            { j = idx;             w = 160; stride = 8;  hw = HW0; bb = bb0 + (size_t)b * 4 * HW0; }
        else if (idx < HW0 + HW1) { j = idx - HW0;       w = 80;  stride = 16; hw = HW1; bb = bb1 + (size_t)b * 4 * HW1; }
        else                      { j = idx - HW0 - HW1; w = 40;  stride = 32; hw = HW2; bb = bb2 + (size_t)b * 4 * HW2; }

        float px = (float)((j % w) * stride);
        float py = (float)((j / w) * stride);
        float l0 = bb[j];
        float t0 = bb[hw + j];
        float r0 = bb[2 * hw + j];
        float d0 = bb[3 * hw + j];

        float* ob = out + ((size_t)b * KTOP + r) * 4;
        ob[0] = px - l0;
        ob[1] = py - t0;
        ob[2] = px + r0;
        ob[3] = py + d0;
        out[score_base + (size_t)b * KTOP + r] = score;
    }
}

extern "C" void kernel_launch(void* const* d_in, const int* in_sizes, int n_in,
                              void* d_out, int out_size, void* d_ws, size_t ws_size,
                              hipStream_t stream) {
    const float* cls0 = (const float*)d_in[0];
    const float* bb0  = (const float*)d_in[1];
    const float* cls1 = (const float*)d_in[2];
    const float* bb1  = (const float*)d_in[3];
    const float* cls2 = (const float*)d_in[4];
    const float* bb2  = (const float*)d_in[5];
    float* out = (float*)d_out;

    const int B = in_sizes[0] / HW0;  // 128

    // workspace layout
    const size_t histBytes = (size_t)B * NBIN * sizeof(uint32_t);      // 1 MB
    const size_t bOff      = histBytes;                                // boundary
    const size_t cOff      = bOff + (size_t)B * sizeof(uint32_t);      // counters
    size_t candOff         = cOff + (size_t)B * sizeof(uint32_t);
    candOff = (candOff + 7) & ~(size_t)7;                              // 8B align
    const size_t need      = candOff + (size_t)B * CAP * sizeof(unsigned long long);

    if (ws_size < need) {
        // fallback: proven monolithic kernel (no workspace required)
        topk_decode_kernel<<<B, 1024, 0, stream>>>(cls0, bb0, cls1, bb1, cls2, bb2, out, B);
        return;
    }

    uint32_t* g_hist            = (uint32_t*)d_ws;
    uint32_t* g_boundary        = (uint32_t*)((char*)d_ws + bOff);
    uint32_t* g_cnt             = (uint32_t*)((char*)d_ws + cOff);
    unsigned long long* g_cand  = (unsigned long long*)((char*)d_ws + candOff);

    hipMemsetAsync(d_ws, 0, histBytes, stream);
    k1_hist<<<B * CHUNKS, SWTH, 0, stream>>>(cls0, cls1, cls2, g_hist);
    k2_boundary<<<B, SWTH, 0, stream>>>(g_hist, g_boundary, g_cnt);
    k3_compact<<<B * CHUNKS, SWTH, 0, stream>>>(cls0, cls1, cls2, g_boundary, g_cnt, g_cand);
    k4_sort_out<<<B, 1024, 0, stream>>>(bb0, bb1, bb2, g_cnt, g_cand, out, B);
}

// Round 3
// 167.121 us; speedup vs baseline: 2.0224x; 2.0224x over previous
//
#include <hip/hip_runtime.h>
#include <stdint.h>

#define NPOS  33600
#define KTOP  1000
#define NBIN  2048
#define CAP   4096

// sizes per level
#define HW0 25600  // 160x160, stride 8
#define HW1 6400   // 80x80,  stride 16
#define HW2 1600   // 40x40,  stride 32

#define NF4   (NPOS / 4)   // 8400 float4 per batch
#define CHUNKS 16          // blocks per batch for sweep kernels
#define SWTH  256          // threads for sweep kernels
#define PERBLK ((NF4 + CHUNKS - 1) / CHUNKS)   // 525 float4 = 2100 elems
#define CNTSTRIDE 16       // pad counters to 64B to avoid false sharing

__device__ __forceinline__ uint32_t mono_key(float x) {
    uint32_t u = __float_as_uint(x);
    return (u & 0x80000000u) ? ~u : (u | 0x80000000u);
}

__device__ __forceinline__ float load_cls(const float* cb0, const float* cb1,
                                          const float* cb2, int i) {
    if (i < HW0)            return cb0[i];
    if (i < HW0 + HW1)      return cb1[i - HW0];
    return cb2[i - HW0 - HW1];
}

// float4 load of elements [4*i4 .. 4*i4+3] (level boundaries are /4)
__device__ __forceinline__ float4 load_cls4(const float* cb0, const float* cb1,
                                            const float* cb2, int i4) {
    int i = i4 * 4;
    if (i < HW0)            return ((const float4*)cb0)[i4];
    if (i < HW0 + HW1)      return ((const float4*)(cb1))[i4 - HW0 / 4];
    return ((const float4*)(cb2))[i4 - (HW0 + HW1) / 4];
}

// ---------------- K1: per-batch histogram, full-GPU parallel ----------------
__global__ __launch_bounds__(SWTH) void k1_hist(
    const float* __restrict__ cls0, const float* __restrict__ cls1,
    const float* __restrict__ cls2, uint32_t* __restrict__ g_hist)
{
    const int b = blockIdx.x / CHUNKS;
    const int c = blockIdx.x % CHUNKS;
    const int tid = threadIdx.x;

    __shared__ uint32_t hist[NBIN];
    for (int i = tid; i < NBIN; i += SWTH) hist[i] = 0u;
    __syncthreads();

    const float* cb0 = cls0 + (size_t)b * HW0;
    const float* cb1 = cls1 + (size_t)b * HW1;
    const float* cb2 = cls2 + (size_t)b * HW2;

    const int lo = c * PERBLK;
    const int hi = min(lo + PERBLK, NF4);
    for (int i4 = lo + tid; i4 < hi; i4 += SWTH) {
        float4 v = load_cls4(cb0, cb1, cb2, i4);
        atomicAdd(&hist[mono_key(v.x) >> 21], 1u);
        atomicAdd(&hist[mono_key(v.y) >> 21], 1u);
        atomicAdd(&hist[mono_key(v.z) >> 21], 1u);
        atomicAdd(&hist[mono_key(v.w) >> 21], 1u);
    }
    __syncthreads();

    uint32_t* gh = g_hist + (size_t)b * NBIN;
    for (int i = tid; i < NBIN; i += SWTH) {
        uint32_t h = hist[i];
        if (h) atomicAdd(&gh[i], h);
    }
}

// ---------------- K2: suffix scan -> boundary per batch ----------------
__global__ __launch_bounds__(SWTH) void k2_boundary(
    const uint32_t* __restrict__ g_hist, uint32_t* __restrict__ g_boundary,
    uint32_t* __restrict__ g_cnt)
{
    const int b = blockIdx.x;
    const int tid = threadIdx.x;
    __shared__ uint32_t hA[NBIN];
    __shared__ uint32_t hB[NBIN];

    const uint32_t* gh = g_hist + (size_t)b * NBIN;
    for (int i = tid; i < NBIN; i += SWTH) hA[i] = gh[i];
    __syncthreads();

    uint32_t* A = hA; uint32_t* Bp = hB;
    for (int off = 1; off < NBIN; off <<= 1) {
        for (int i = tid; i < NBIN; i += SWTH)
            Bp[i] = A[i] + ((i + off < NBIN) ? A[i + off] : 0u);
        __syncthreads();
        uint32_t* t = A; A = Bp; Bp = t;
    }
    for (int bin = tid; bin < NBIN; bin += SWTH) {
        uint32_t c     = A[bin];
        uint32_t cnext = (bin + 1 < NBIN) ? A[bin + 1] : 0u;
        if (c >= (uint32_t)KTOP && cnext < (uint32_t)KTOP) g_boundary[b] = (uint32_t)bin;
    }
    if (tid == 0) {
        // safety: if top bin alone holds >= KTOP (tie-heavy), crossing never fires
        if (A[NBIN - 1] >= (uint32_t)KTOP) g_boundary[b] = (uint32_t)(NBIN - 1);
        g_cnt[(size_t)b * CNTSTRIDE] = 0u;
    }
}

// ---------------- K3: compact candidates, LDS-staged ----------------
__global__ __launch_bounds__(SWTH) void k3_compact(
    const float* __restrict__ cls0, const float* __restrict__ cls1,
    const float* __restrict__ cls2, const uint32_t* __restrict__ g_boundary,
    uint32_t* __restrict__ g_cnt, unsigned long long* __restrict__ g_cand)
{
    const int b = blockIdx.x / CHUNKS;
    const int c = blockIdx.x % CHUNKS;
    const int tid = threadIdx.x;

    __shared__ unsigned long long lbuf[PERBLK * 4 + 8];  // worst case: all pass
    __shared__ uint32_t s_n;
    __shared__ uint32_t s_base;
    if (tid == 0) s_n = 0u;
    __syncthreads();

    const uint32_t boundary = g_boundary[b];
    const float* cb0 = cls0 + (size_t)b * HW0;
    const float* cb1 = cls1 + (size_t)b * HW1;
    const float* cb2 = cls2 + (size_t)b * HW2;

    const int lo = c * PERBLK;
    const int hi = min(lo + PERBLK, NF4);
    for (int i4 = lo + tid; i4 < hi; i4 += SWTH) {
        float4 v = load_cls4(cb0, cb1, cb2, i4);
        float vv[4] = {v.x, v.y, v.z, v.w};
        #pragma unroll
        for (int e = 0; e < 4; e++) {
            uint32_t k = mono_key(vv[e]);
            if ((k >> 21) >= boundary) {
                uint32_t p = atomicAdd(&s_n, 1u);   // LDS atomic: cheap
                int idx = i4 * 4 + e;
                lbuf[p] = ((unsigned long long)k << 16)
                        | (unsigned long long)(65535 - idx);
            }
        }
    }
    __syncthreads();

    const uint32_t n = s_n;
    if (tid == 0) s_base = atomicAdd(&g_cnt[(size_t)b * CNTSTRIDE], n); // 1 global atomic/block
    __syncthreads();
    const uint32_t base = s_base;
    unsigned long long* cand = g_cand + (size_t)b * CAP;
    for (uint32_t i = tid; i < n; i += SWTH) {
        uint32_t pos = base + i;
        if (pos < CAP) cand[pos] = lbuf[i];
    }
}

// ---------------- K4: sort + decode + write ----------------
__global__ __launch_bounds__(1024) void k4_sort_out(
    const float* __restrict__ bb0, const float* __restrict__ bb1,
    const float* __restrict__ bb2, const uint32_t* __restrict__ g_cnt,
    const unsigned long long* __restrict__ g_cand,
    float* __restrict__ out, int B)
{
    const int b = blockIdx.x;
    const int tid = threadIdx.x;
    __shared__ unsigned long long buf[CAP];

    int cnt = (int)g_cnt[(size_t)b * CNTSTRIDE]; if (cnt > CAP) cnt = CAP;
    const unsigned long long* cand = g_cand + (size_t)b * CAP;
    for (int i = tid; i < cnt; i += 1024) buf[i] = cand[i];

    int M = 1024; while (M < cnt) M <<= 1;
    for (int i = cnt + tid; i < M; i += 1024) buf[i] = 0ull;
    __syncthreads();

    for (int k = 2; k <= M; k <<= 1) {
        for (int j = k >> 1; j > 0; j >>= 1) {
            for (int i = tid; i < M; i += 1024) {
                int l = i ^ j;
                if (l > i) {
                    unsigned long long a = buf[i], c2 = buf[l];
                    bool sw = ((i & k) == 0) ? (a < c2) : (a > c2);
                    if (sw) { buf[i] = c2; buf[l] = a; }
                }
            }
            __syncthreads();
        }
    }

    const size_t score_base = (size_t)B * KTOP * 4;
    for (int r = tid; r < KTOP; r += 1024) {
        unsigned long long ck = buf[r];
        uint32_t k = (uint32_t)(ck >> 16);
        int idx    = 65535 - (int)(ck & 0xFFFFull);

        uint32_t u = (k & 0x80000000u) ? (k ^ 0x80000000u) : ~k;
        float logit = __uint_as_float(u);
        float score = 1.0f / (1.0f + expf(-logit));

        int j, w, stride, hw;
        const float* bb;
        if (idx < HW0)            { j = idx;             w = 160; stride = 8;  hw = HW0; bb = bb0 + (size_t)b * 4 * HW0; }
        else if (idx < HW0 + HW1) { j = idx - HW0;       w = 80;  stride = 16; hw = HW1; bb = bb1 + (size_t)b * 4 * HW1; }
        else                      { j = idx - HW0 - HW1; w = 40;  stride = 32; hw = HW2; bb = bb2 + (size_t)b * 4 * HW2; }

        float px = (float)((j % w) * stride);
        float py = (float)((j / w) * stride);
        float l0 = bb[j];
        float t0 = bb[hw + j];
        float r0 = bb[2 * hw + j];
        float d0 = bb[3 * hw + j];

        float* ob = out + ((size_t)b * KTOP + r) * 4;
        ob[0] = px - l0;
        ob[1] = py - t0;
        ob[2] = px + r0;
        ob[3] = py + d0;
        out[score_base + (size_t)b * KTOP + r] = score;
    }
}

// ---------------- fallback: round-1 monolithic kernel ----------------
__global__ __launch_bounds__(1024) void topk_decode_kernel(
    const float* __restrict__ cls0, const float* __restrict__ bb0,
    const float* __restrict__ cls1, const float* __restrict__ bb1,
    const float* __restrict__ cls2, const float* __restrict__ bb2,
    float* __restrict__ out, int B)
{
    const int b   = blockIdx.x;
    const int tid = threadIdx.x;

    __shared__ uint32_t histA[NBIN];
    __shared__ uint32_t histB[NBIN];
    __shared__ unsigned long long buf[CAP];
    __shared__ int s_boundary;
    __shared__ int s_cnt;

    for (int i = tid; i < NBIN; i += 1024) histA[i] = 0u;
    if (tid == 0) s_cnt = 0;
    __syncthreads();

    const float* cb0 = cls0 + (size_t)b * HW0;
    const float* cb1 = cls1 + (size_t)b * HW1;
    const float* cb2 = cls2 + (size_t)b * HW2;

    for (int i = tid; i < NPOS; i += 1024) {
        float v = load_cls(cb0, cb1, cb2, i);
        atomicAdd(&histA[mono_key(v) >> 21], 1u);
    }
    __syncthreads();

    uint32_t* A = histA; uint32_t* Bp = histB;
    for (int off = 1; off < NBIN; off <<= 1) {
        for (int i = tid; i < NBIN; i += 1024)
            Bp[i] = A[i] + ((i + off < NBIN) ? A[i + off] : 0u);
        __syncthreads();
        uint32_t* t = A; A = Bp; Bp = t;
    }
    for (int bin = tid; bin < NBIN; bin += 1024) {
        uint32_t c     = A[bin];
        uint32_t cnext = (bin + 1 < NBIN) ? A[bin + 1] : 0u;
        if (c >= (uint32_t)KTOP && cnext < (uint32_t)KTOP) s_boundary = bin;
    }
    if (tid == 0 && A[NBIN - 1] >= (uint32_t)KTOP) s_boundary = NBIN - 1;
    __syncthreads();
    const uint32_t boundary = (uint32_t)s_boundary;

    for (int i = tid; i < NPOS; i += 1024) {
        float v = load_cls(cb0, cb1, cb2, i);
        uint32_t k = mono_key(v);
        if ((k >> 21) >= boundary) {
            int pos = atomicAdd(&s_cnt, 1);
            if (pos < CAP)
                buf[pos] = ((unsigned long long)k << 16)
                         | (unsigned long long)(65535 - i);
        }
    }
    __syncthreads();
    int cnt = s_cnt; if (cnt > CAP) cnt = CAP;
    int M = 1024; while (M < cnt) M <<= 1;
    for (int i = cnt + tid; i < M; i += 1024) buf[i] = 0ull;
    __syncthreads();

    for (int k = 2; k <= M; k <<= 1) {
        for (int j = k >> 1; j > 0; j >>= 1) {
            for (int i = tid; i < M; i += 1024) {
                int l = i ^ j;
                if (l > i) {
                    unsigned long long a = buf[i], c = buf[l];
                    bool sw = ((i & k) == 0) ? (a < c) : (a > c);
                    if (sw) { buf[i] = c; buf[l] = a; }
                }
            }
            __syncthreads();
        }
    }

    const size_t score_base = (size_t)B * KTOP * 4;
    for (int r = tid; r < KTOP; r += 1024) {
        unsigned long long ck = buf[r];
        uint32_t k = (uint32_t)(ck >> 16);
        int idx    = 65535 - (int)(ck & 0xFFFFull);

        uint32_t u = (k & 0x80000000u) ? (k ^ 0x80000000u) : ~k;
        float logit = __uint_as_float(u);
        float score = 1.0f / (1.0f + expf(-logit));

        int j, w, stride, hw;
        const float* bb;
        if (idx < HW0)            { j = idx;             w = 160; stride = 8;  hw = HW0; bb = bb0 + (size_t)b * 4 * HW0; }
        else if (idx < HW0 + HW1) { j = idx - HW0;       w = 80;  stride = 16; hw = HW1; bb = bb1 + (size_t)b * 4 * HW1; }
        else                      { j = idx - HW0 - HW1; w = 40;  stride = 32; hw = HW2; bb = bb2 + (size_t)b * 4 * HW2; }

        float px = (float)((j % w) * stride);
        float py = (float)((j / w) * stride);
        float l0 = bb[j];
        float t0 = bb[hw + j];
        float r0 = bb[2 * hw + j];
        float d0 = bb[3 * hw + j];

        float* ob = out + ((size_t)b * KTOP + r) * 4;
        ob[0] = px - l0;
        ob[1] = py - t0;
        ob[2] = px + r0;
        ob[3] = py + d0;
        out[score_base + (size_t)b * KTOP + r] = score;
    }
}

extern "C" void kernel_launch(void* const* d_in, const int* in_sizes, int n_in,
                              void* d_out, int out_size, void* d_ws, size_t ws_size,
                              hipStream_t stream) {
    const float* cls0 = (const float*)d_in[0];
    const float* bb0  = (const float*)d_in[1];
    const float* cls1 = (const float*)d_in[2];
    const float* bb1  = (const float*)d_in[3];
    const float* cls2 = (const float*)d_in[4];
    const float* bb2  = (const float*)d_in[5];
    float* out = (float*)d_out;

    const int B = in_sizes[0] / HW0;  // 128

    // workspace layout
    const size_t histBytes = (size_t)B * NBIN * sizeof(uint32_t);      // 1 MB
    const size_t bOff      = histBytes;                                // boundary
    const size_t cOff      = bOff + (size_t)B * sizeof(uint32_t);      // counters (64B-strided)
    size_t candOff         = cOff + (size_t)B * CNTSTRIDE * sizeof(uint32_t);
    candOff = (candOff + 7) & ~(size_t)7;                              // 8B align
    const size_t need      = candOff + (size_t)B * CAP * sizeof(unsigned long long);

    if (ws_size < need) {
        topk_decode_kernel<<<B, 1024, 0, stream>>>(cls0, bb0, cls1, bb1, cls2, bb2, out, B);
        return;
    }

    uint32_t* g_hist            = (uint32_t*)d_ws;
    uint32_t* g_boundary        = (uint32_t*)((char*)d_ws + bOff);
    uint32_t* g_cnt             = (uint32_t*)((char*)d_ws + cOff);
    unsigned long long* g_cand  = (unsigned long long*)((char*)d_ws + candOff);

    hipMemsetAsync(d_ws, 0, histBytes, stream);
    k1_hist<<<B * CHUNKS, SWTH, 0, stream>>>(cls0, cls1, cls2, g_hist);
    k2_boundary<<<B, SWTH, 0, stream>>>(g_hist, g_boundary, g_cnt);
    k3_compact<<<B * CHUNKS, SWTH, 0, stream>>>(cls0, cls1, cls2, g_boundary, g_cnt, g_cand);
    k4_sort_out<<<B, 1024, 0, stream>>>(bb0, bb1, bb2, g_cnt, g_cand, out, B);
}